// Round 6
// baseline (858.722 us; speedup 1.0000x reference)
//
#include <hip/hip_runtime.h>
#include <hip/hip_fp16.h>

constexpr int kN  = 50000;
constexpr int kE  = 400000;
constexpr int kHC = 128;
constexpr int kED = 32;
constexpr int kL  = 2;
#define EPS_LN 1e-5f
#define NEG_SLOPE 0.01f
#define RSQRT_C 0.17677669529663687f  // 1/sqrt(32)

// ---------------- Projections: q,k,v,xr = h @ {Wq,Wk,Wv,Wskip} + b ----------
__global__ __launch_bounds__(256) void proj_kernel(
    const float* __restrict__ hin,
    const float* __restrict__ Wq, const float* __restrict__ bq,
    const float* __restrict__ Wk, const float* __restrict__ bk,
    const float* __restrict__ Wv, const float* __restrict__ bv,
    const float* __restrict__ Ws, const float* __restrict__ bs,
    float* __restrict__ q, float* __restrict__ k,
    float* __restrict__ v, float* __restrict__ xr)
{
    __shared__ float xs[16 * kHC];
    const int t = threadIdx.x;
    const int row0 = blockIdx.x * 16;
    const float4* s4 = (const float4*)(hin + (size_t)row0 * kHC);
    float4* d4 = (float4*)xs;
    d4[t] = s4[t];
    d4[t + 256] = s4[t + 256];
    __syncthreads();

    const int c = t & 127;
    const int half = t >> 7;
    float acc0[8], acc1[8], acc2[8], acc3[8];
#pragma unroll
    for (int r = 0; r < 8; r++) { acc0[r] = 0.f; acc1[r] = 0.f; acc2[r] = 0.f; acc3[r] = 0.f; }
    const float* xbase = xs + (half * 8) * kHC;

    for (int k4 = 0; k4 < kHC; k4 += 4) {
        float4 xv[8];
#pragma unroll
        for (int r = 0; r < 8; r++) xv[r] = *(const float4*)(xbase + r * kHC + k4);
#pragma unroll
        for (int i = 0; i < 4; i++) {
            const int ki = k4 + i;
            const float wq = Wq[ki * kHC + c];
            const float wk = Wk[ki * kHC + c];
            const float wv = Wv[ki * kHC + c];
            const float wsv = Ws[ki * kHC + c];
#pragma unroll
            for (int r = 0; r < 8; r++) {
                const float xvi = ((const float*)&xv[r])[i];
                acc0[r] = fmaf(xvi, wq, acc0[r]);
                acc1[r] = fmaf(xvi, wk, acc1[r]);
                acc2[r] = fmaf(xvi, wv, acc2[r]);
                acc3[r] = fmaf(xvi, wsv, acc3[r]);
            }
        }
    }
    const float bqv = bq[c], bkv = bk[c], bvv = bv[c], bsv = bs[c];
#pragma unroll
    for (int r = 0; r < 8; r++) {
        const size_t o = (size_t)(row0 + half * 8 + r) * kHC + c;
        q[o]  = acc0[r] + bqv;
        k[o]  = acc1[r] + bkv;
        v[o]  = acc2[r] + bvv;
        xr[o] = acc3[r] + bsv;
    }
}

// ---------------- CSR build (once per call) ---------------------------------
__global__ __launch_bounds__(256) void hist_kernel(
    const int* __restrict__ dstI, int* __restrict__ deg)
{
    const int e = blockIdx.x * 256 + threadIdx.x;
    if (e < kE) atomicAdd(&deg[dstI[e]], 1);
}

__global__ __launch_bounds__(1024) void scan_kernel(
    const int* __restrict__ deg, int* __restrict__ rowptr, int* __restrict__ cursor)
{
    const int t = threadIdx.x;
    constexpr int CH = (kN + 1023) / 1024;
    const int base = t * CH;
    const int end = base + CH < kN ? base + CH : kN;
    int lsum = 0;
    for (int i = base; i < end; i++) lsum += deg[i];
    __shared__ int sm[1024];
    sm[t] = lsum;
    __syncthreads();
    for (int off = 1; off < 1024; off <<= 1) {
        const int x = (t >= off) ? sm[t - off] : 0;
        __syncthreads();
        sm[t] += x;
        __syncthreads();
    }
    int running = sm[t] - lsum;
    for (int i = base; i < end; i++) {
        rowptr[i] = running;
        cursor[i] = running;
        running += deg[i];
    }
    if (t == 1023) rowptr[kN] = sm[1023];
}

__global__ __launch_bounds__(256) void scatter_kernel(
    const int* __restrict__ srcI, const int* __restrict__ dstI,
    int* __restrict__ cursor, int* __restrict__ esrc, int* __restrict__ eidx)
{
    const int e = blockIdx.x * 256 + threadIdx.x;
    if (e >= kE) return;
    const int d = dstI[e];
    const int pos = atomicAdd(&cursor[d], 1);
    esrc[pos] = srcI[e];
    eidx[pos] = e;
}

// ---------------- Edge precompute: ke/ve (fp16) in CSR order ----------------
// Wave processes a contiguous chunk of CSR positions; We slice loaded once.
constexpr int kPreWaves = 16384;  // 4096 blocks x 4 waves
__global__ __launch_bounds__(256) void edge_pre_kernel(
    const float* __restrict__ kk, const float* __restrict__ vv,
    const float* __restrict__ ea,
    const float* __restrict__ We, const float* __restrict__ be,
    const int* __restrict__ esrc, const int* __restrict__ eidx,
    __half* __restrict__ kv)
{
    const int t = threadIdx.x;
    const int wid = blockIdx.x * 4 + (t >> 6);
    const int lane = t & 63;
    const int c = lane << 1;

    float we0[kED], we1[kED];
#pragma unroll
    for (int j = 0; j < kED; j++) {
        const float2 w = *(const float2*)&We[j * kHC + c];
        we0[j] = w.x; we1[j] = w.y;
    }
    const float be0 = be[c], be1 = be[c + 1];

    constexpr int CH = (kE + kPreWaves - 1) / kPreWaves;  // 25
    const int j0 = wid * CH;
    const int j1 = (j0 + CH < kE) ? j0 + CH : kE;
    for (int jj = j0; jj < j1; jj++) {
        const int s   = esrc[jj];
        const int eid = eidx[jj];
        const float a = ea[(size_t)eid * kED + (lane & 31)];
        float e0 = be0, e1 = be1;
#pragma unroll
        for (int j = 0; j < kED; j++) {
            const float aj = __shfl(a, j, 32);
            e0 = fmaf(aj, we0[j], e0);
            e1 = fmaf(aj, we1[j], e1);
        }
        const float2 kvv = *(const float2*)&kk[(size_t)s * kHC + c];
        const float2 vl  = *(const float2*)&vv[(size_t)s * kHC + c];
        __half2* o0 = (__half2*)&kv[(size_t)jj * 256 + c];
        __half2* o1 = (__half2*)&kv[(size_t)jj * 256 + 128 + c];
        *o0 = __floats2half2_rn(kvv.x + e0, kvv.y + e1);
        *o1 = __floats2half2_rn(vl.x + e0, vl.y + e1);
    }
}

// ---------------- Fused per-node aggregation + epilogue (sequential streams)
__global__ __launch_bounds__(256) void fused_kernel(
    const float* __restrict__ q, const __half* __restrict__ kv,
    const int* __restrict__ rowptr,
    const float* __restrict__ xr, const float* __restrict__ Wb,
    const float* __restrict__ lnw, const float* __restrict__ lnb,
    float* __restrict__ hout)
{
    const int t = threadIdx.x;
    const int n = blockIdx.x * 4 + (t >> 6);
    if (n >= kN) return;
    const int lane = t & 63;
    const int c = lane << 1;

    const float2 qv = *(const float2*)&q[(size_t)n * kHC + c];
    float acc0 = 0.f, acc1 = 0.f, den = 0.f;
    const int beg = rowptr[n], endp = rowptr[n + 1];
    const __half2* kvh = (const __half2*)kv;
    for (int jj = beg; jj < endp; jj++) {
        const float2 kf = __half22float2(kvh[(size_t)jj * 128 + lane]);
        const float2 vf = __half22float2(kvh[(size_t)jj * 128 + 64 + lane]);
        float p = qv.x * kf.x + qv.y * kf.y;
        p += __shfl_xor(p, 1);
        p += __shfl_xor(p, 2);
        p += __shfl_xor(p, 4);
        p += __shfl_xor(p, 8);
        const float aex = __expf(p * RSQRT_C);
        den += aex;
        acc0 = fmaf(vf.x, aex, acc0);
        acc1 = fmaf(vf.y, aex, acc1);
    }
    const float invd = 1.f / (den + 1e-16f);
    const float o0 = acc0 * invd, o1 = acc1 * invd;

    const float2 r = *(const float2*)&xr[(size_t)n * kHC + c];
    float z = o0 * Wb[c] + o1 * Wb[c + 1]
            + r.x * Wb[kHC + c] + r.y * Wb[kHC + c + 1]
            + (o0 - r.x) * Wb[2 * kHC + c] + (o1 - r.y) * Wb[2 * kHC + c + 1];
#pragma unroll
    for (int m = 1; m < 64; m <<= 1) z += __shfl_xor(z, m);
    const float beta = 1.f / (1.f + __expf(-z));

    const float g0 = beta * r.x + (1.f - beta) * o0;
    const float g1 = beta * r.y + (1.f - beta) * o1;

    float sm = g0 + g1;
    float sq = g0 * g0 + g1 * g1;
#pragma unroll
    for (int m = 1; m < 64; m <<= 1) {
        sm += __shfl_xor(sm, m);
        sq += __shfl_xor(sq, m);
    }
    const float mu  = sm * (1.f / kHC);
    const float var = sq * (1.f / kHC) - mu * mu;
    const float inv = rsqrtf(var + EPS_LN);

    float y0 = (g0 - mu) * inv * lnw[c] + lnb[c];
    float y1 = (g1 - mu) * inv * lnw[c + 1] + lnb[c + 1];
    y0 = y0 > 0.f ? y0 : NEG_SLOPE * y0;
    y1 = y1 > 0.f ? y1 : NEG_SLOPE * y1;
    *(float2*)&hout[(size_t)n * kHC + c] = make_float2(y0, y1);
}

// ---------------- Fallback fused (round-4 path, used if ws too small) -------
__global__ __launch_bounds__(256) void fused_kernel_fb(
    const float* __restrict__ q, const float* __restrict__ kk,
    const float* __restrict__ vv, const float* __restrict__ ea,
    const float* __restrict__ We, const float* __restrict__ be,
    const int* __restrict__ rowptr, const int* __restrict__ esrc,
    const int* __restrict__ eidx,
    const float* __restrict__ xr, const float* __restrict__ Wb,
    const float* __restrict__ lnw, const float* __restrict__ lnb,
    float* __restrict__ hout)
{
    const int t = threadIdx.x;
    const int n = blockIdx.x * 4 + (t >> 6);
    if (n >= kN) return;
    const int lane = t & 63;
    const int c = lane << 1;

    float we0[kED], we1[kED];
#pragma unroll
    for (int j = 0; j < kED; j++) {
        const float2 w = *(const float2*)&We[j * kHC + c];
        we0[j] = w.x; we1[j] = w.y;
    }
    const float be0 = be[c], be1 = be[c + 1];
    const float2 qv = *(const float2*)&q[(size_t)n * kHC + c];

    float acc0 = 0.f, acc1 = 0.f, den = 0.f;
    const int beg = rowptr[n], endp = rowptr[n + 1];
    for (int jj = beg; jj < endp; jj++) {
        const int s   = esrc[jj];
        const int eid = eidx[jj];
        const float a = ea[(size_t)eid * kED + (lane & 31)];
        float e0 = be0, e1 = be1;
#pragma unroll
        for (int j = 0; j < kED; j++) {
            const float aj = __shfl(a, j, 32);
            e0 = fmaf(aj, we0[j], e0);
            e1 = fmaf(aj, we1[j], e1);
        }
        const float2 kvv = *(const float2*)&kk[(size_t)s * kHC + c];
        const float2 vl = *(const float2*)&vv[(size_t)s * kHC + c];
        float p = qv.x * (kvv.x + e0) + qv.y * (kvv.y + e1);
        p += __shfl_xor(p, 1);
        p += __shfl_xor(p, 2);
        p += __shfl_xor(p, 4);
        p += __shfl_xor(p, 8);
        const float aex = __expf(p * RSQRT_C);
        den += aex;
        acc0 = fmaf(vl.x + e0, aex, acc0);
        acc1 = fmaf(vl.y + e1, aex, acc1);
    }
    const float invd = 1.f / (den + 1e-16f);
    const float o0 = acc0 * invd, o1 = acc1 * invd;

    const float2 r = *(const float2*)&xr[(size_t)n * kHC + c];
    float z = o0 * Wb[c] + o1 * Wb[c + 1]
            + r.x * Wb[kHC + c] + r.y * Wb[kHC + c + 1]
            + (o0 - r.x) * Wb[2 * kHC + c] + (o1 - r.y) * Wb[2 * kHC + c + 1];
#pragma unroll
    for (int m = 1; m < 64; m <<= 1) z += __shfl_xor(z, m);
    const float beta = 1.f / (1.f + __expf(-z));

    const float g0 = beta * r.x + (1.f - beta) * o0;
    const float g1 = beta * r.y + (1.f - beta) * o1;

    float sm = g0 + g1;
    float sq = g0 * g0 + g1 * g1;
#pragma unroll
    for (int m = 1; m < 64; m <<= 1) {
        sm += __shfl_xor(sm, m);
        sq += __shfl_xor(sq, m);
    }
    const float mu  = sm * (1.f / kHC);
    const float var = sq * (1.f / kHC) - mu * mu;
    const float inv = rsqrtf(var + EPS_LN);

    float y0 = (g0 - mu) * inv * lnw[c] + lnb[c];
    float y1 = (g1 - mu) * inv * lnw[c + 1] + lnb[c + 1];
    y0 = y0 > 0.f ? y0 : NEG_SLOPE * y0;
    y1 = y1 > 0.f ? y1 : NEG_SLOPE * y1;
    *(float2*)&hout[(size_t)n * kHC + c] = make_float2(y0, y1);
}

extern "C" void kernel_launch(void* const* d_in, const int* in_sizes, int n_in,
                              void* d_out, int out_size, void* d_ws, size_t ws_size,
                              hipStream_t stream)
{
    const float* x   = (const float*)d_in[0];
    const int*   ei  = (const int*)d_in[1];
    const float* ea  = (const float*)d_in[2];
    const float* Wq  = (const float*)d_in[3];
    const float* bq  = (const float*)d_in[4];
    const float* Wk  = (const float*)d_in[5];
    const float* bk  = (const float*)d_in[6];
    const float* Wv  = (const float*)d_in[7];
    const float* bv  = (const float*)d_in[8];
    const float* We  = (const float*)d_in[9];
    const float* be  = (const float*)d_in[10];
    const float* Wsk = (const float*)d_in[11];
    const float* bsk = (const float*)d_in[12];
    const float* Wb  = (const float*)d_in[13];
    const float* lnw = (const float*)d_in[14];
    const float* lnb = (const float*)d_in[15];
    float* out = (float*)d_out;

    float* ws = (float*)d_ws;
    float* q  = ws;
    float* k  = q  + (size_t)kN * kHC;
    float* v  = k  + (size_t)kN * kHC;
    float* xr = v  + (size_t)kN * kHC;
    int* deg    = (int*)(xr + (size_t)kN * kHC);
    int* rowptr = deg + kN;
    int* cursor = rowptr + kN + 1;
    int* esrc   = cursor + kN;
    int* eidx   = esrc + kE;
    __half* kv  = (__half*)(eidx + kE);

    const size_t need = (size_t)(eidx + kE - (int*)d_ws) * 4 + (size_t)kE * 256 * 2;
    const bool big = ws_size >= need;

    const int* srcI = ei;
    const int* dstI = ei + kE;

    hipMemsetAsync(deg, 0, (size_t)kN * sizeof(int), stream);
    hist_kernel<<<(kE + 255) / 256, 256, 0, stream>>>(dstI, deg);
    scan_kernel<<<1, 1024, 0, stream>>>(deg, rowptr, cursor);
    scatter_kernel<<<(kE + 255) / 256, 256, 0, stream>>>(srcI, dstI, cursor, esrc, eidx);

    const float* hin = x;
    for (int l = 0; l < kL; l++) {
        proj_kernel<<<kN / 16, 256, 0, stream>>>(
            hin,
            Wq + (size_t)l * kHC * kHC, bq + (size_t)l * kHC,
            Wk + (size_t)l * kHC * kHC, bk + (size_t)l * kHC,
            Wv + (size_t)l * kHC * kHC, bv + (size_t)l * kHC,
            Wsk + (size_t)l * kHC * kHC, bsk + (size_t)l * kHC,
            q, k, v, xr);
        if (big) {
            edge_pre_kernel<<<kPreWaves / 4, 256, 0, stream>>>(
                k, v, ea,
                We + (size_t)l * kED * kHC, be + (size_t)l * kHC,
                esrc, eidx, kv);
            fused_kernel<<<(kN + 3) / 4, 256, 0, stream>>>(
                q, kv, rowptr,
                xr, Wb + (size_t)l * 3 * kHC,
                lnw + (size_t)l * kHC, lnb + (size_t)l * kHC,
                out);
        } else {
            fused_kernel_fb<<<(kN + 3) / 4, 256, 0, stream>>>(
                q, k, v, ea,
                We + (size_t)l * kED * kHC, be + (size_t)l * kHC,
                rowptr, esrc, eidx,
                xr, Wb + (size_t)l * 3 * kHC,
                lnw + (size_t)l * kHC, lnb + (size_t)l * kHC,
                out);
        }
        hin = out;
    }
}